// Round 14
// baseline (377.835 us; speedup 1.0000x reference)
//
#include <hip/hip_runtime.h>

// EdgeBlock: out = relu(concat(node[snd], node[rcv], edge) @ w1 + b1) @ w2 + b2
// E=800000, N=50000, D=128. fp32 in/out, fp16 MFMA.
// r14 = r11's structure/order with 16x16x32 MFMA tiles (16 edges/wave):
//   per-wave A/h buffer 8KB->4KB  =>  1024-thr block, 16 waves,
//   LDS = 96KB w1t + 16*4KB = 160KB  =>  16 waves/CU (2x r11's occupancy).
//   All gather/acc register batches halve -> fits 128-reg budget (4 waves/SIMD).

#define NE 800000
#define ND 50000
#define DD 128

typedef float f32x4v __attribute__((ext_vector_type(4)));
typedef _Float16 f16x8 __attribute__((ext_vector_type(8)));
typedef _Float16 f16x4 __attribute__((ext_vector_type(4)));

__device__ __forceinline__ f16x4 cvt4(f32x4v v) {
    f16x4 r;
    r[0] = (_Float16)v[0]; r[1] = (_Float16)v[1];
    r[2] = (_Float16)v[2]; r[3] = (_Float16)v[3];
    return r;
}

// w1[384][128] -> w1t swizzled fp16: byte = col*768 + ((k*2) ^ ((col&15)<<4))   (96KB)
// w2[128][128] -> w2f fragment-major fp16: w2f[(ks*128 + col)*8 + j] = w2[ks*8+j][col] (32KB)
__global__ void prep_w(const float* __restrict__ w1, const float* __restrict__ w2,
                       _Float16* __restrict__ w1t, _Float16* __restrict__ w2f) {
    int i = blockIdx.x * 256 + threadIdx.x;   // 65536 total
    if (i < 384 * 128) {
        int col = i / 384;
        int k = i - col * 384;
        float v = w1[(size_t)k * 128 + col];
        int byteoff = col * 768 + ((k * 2) ^ ((col & 15) << 4));
        *(_Float16*)((char*)w1t + byteoff) = (_Float16)v;
    } else {
        int j = i - 384 * 128;                // 0..16383
        int ks = j >> 10;                     // 0..15
        int col = (j >> 3) & 127;
        int jj = j & 7;
        w2f[j] = (_Float16)w2[(size_t)(ks * 8 + jj) * 128 + col];
    }
}

// node_attr fp32 [50000][128] -> nf16 fp16 [50000][128]
__global__ void prep_node(const float* __restrict__ node_attr, _Float16* __restrict__ nf16) {
    int i = blockIdx.x * 256 + threadIdx.x;   // x8 elems: 3125 blocks
    const float* src = node_attr + (size_t)i * 8;
    f32x4v a = *(const f32x4v*)src;
    f32x4v b = *(const f32x4v*)(src + 4);
    f16x8 r;
    r[0] = (_Float16)a[0]; r[1] = (_Float16)a[1];
    r[2] = (_Float16)a[2]; r[3] = (_Float16)a[3];
    r[4] = (_Float16)b[0]; r[5] = (_Float16)b[1];
    r[6] = (_Float16)b[2]; r[7] = (_Float16)b[3];
    *(f16x8*)(nf16 + (size_t)i * 8) = r;
}

// MFMA over one staged segment: 4 K-steps (K=32 each) against w1t seg in LDS.
// A: lane -> row r15, k-slice q16 = (lane>>4)*16 bytes. B: col = n*16+r15.
#define MFMA_SEG(SEG)                                                                     \
    _Pragma("unroll")                                                                     \
    for (int kk = 0; kk < 4; kk++) {                                                      \
        f16x8 a = *(const f16x8*)(ab + r15 * 256 + ((kk * 64 + q16) ^ xa));               \
        _Pragma("unroll")                                                                 \
        for (int n = 0; n < 8; n++) {                                                     \
            const int col = n * 16 + r15;                                                 \
            f16x8 b = *(const f16x8*)(lds + col * 768 +                                   \
                       ((((SEG) * 4 + kk) * 64 + q16) ^ xa));                             \
            acc[n] = __builtin_amdgcn_mfma_f32_16x16x32_f16(a, b, acc[n], 0, 0, 0);       \
        }                                                                                 \
    }

// write a gathered fp16 segment (V = f16x4[8], 2 rows/instr) into ab, swizzled
#define WRITE_SEG16(V)                                                                    \
    _Pragma("unroll")                                                                     \
    for (int i = 0; i < 8; i++) {                                                         \
        const int row = 2 * i + sub;                                                      \
        *(f16x4*)(ab + row * 256 + ((c31 * 8) ^ ((row & 15) << 4))) = V[i];               \
    }

__global__ __attribute__((amdgpu_flat_work_group_size(1024, 1024),
                          amdgpu_waves_per_eu(4, 4)))
void edge_mlp(
    const float* __restrict__ node_attr,   // unused
    const int* __restrict__ eidx,
    const float* __restrict__ edge_attr,
    const _Float16* __restrict__ w1t,   // swizzled, 96KB
    const float* __restrict__ b1,
    const _Float16* __restrict__ w2f,   // fragment-major, 32KB
    const float* __restrict__ b2,
    const _Float16* __restrict__ nf16,  // fp16 node rows, 12.8MB (L3-resident)
    float* __restrict__ out) {
    extern __shared__ char lds[];   // [0,96K): w1t swz   [96K + wid*4K): A/h per wave

    const int tid = threadIdx.x;
    const int wid = tid >> 6;        // 0..15
    const int lane = tid & 63;
    const int r15 = lane & 15;       // MFMA row / col low bits
    const int q16 = (lane >> 4) * 16;// k-slice byte offset
    const int sub = lane >> 5;       // row selector within gathered pair
    const int c31 = lane & 31;       // chunk index within row

    // ---- stage w1t -> LDS ----
    {
        const char* src = (const char*)w1t;
        #pragma unroll
        for (int i = 0; i < 6; i++) {
            int off = (tid + i * 1024) * 16;   // 1024*6*16B = 96KB
            *(f16x8*)(lds + off) = *(const f16x8*)(src + off);
        }
    }

    float b1v[8], b2v[8];
    #pragma unroll
    for (int n = 0; n < 8; n++) { b1v[n] = b1[n * 16 + r15]; b2v[n] = b2[n * 16 + r15]; }

    __syncthreads();

    char* ab = lds + 96 * 1024 + wid * 4096;
    const int xa = r15 << 4;          // swizzle XOR (col&15 == row&15 == r15)
    const int ebase = blockIdx.x * 256 + wid * 16;

    const int sidx = eidx[ebase + r15];
    const int ridx = eidx[NE + ebase + r15];

    // ---- gather sender rows: fp16, 2 rows/instr (2x256B), 8B/lane ----
    f16x4 sv[8];
    #pragma unroll
    for (int i = 0; i < 8; i++) {
        int r = __shfl(sidx, 2 * i + sub);
        sv[i] = *(const f16x4*)(nf16 + (size_t)r * DD + c31 * 4);
    }
    WRITE_SEG16(sv)

    // issue receiver gathers (fly during seg-S MFMAs)
    f16x4 rv[8];
    #pragma unroll
    for (int i = 0; i < 8; i++) {
        int r = __shfl(ridx, 2 * i + sub);
        rv[i] = *(const f16x4*)(nf16 + (size_t)r * DD + c31 * 4);
    }

    typedef float f32x4a __attribute__((ext_vector_type(4)));
    f32x4a acc[8] = {};
    __builtin_amdgcn_wave_barrier();

    // ---- consume seg 0 (sender) ----
    MFMA_SEG(0)

    WRITE_SEG16(rv)
    // issue edge loads (fp32, 2 rows/instr = 2x512B, 16B/lane)
    f32x4v ev[8];
    #pragma unroll
    for (int i = 0; i < 8; i++) {
        const int row = 2 * i + sub;
        ev[i] = __builtin_nontemporal_load(
            (const f32x4v*)(edge_attr + (size_t)(ebase + row) * DD + c31 * 4));
    }
    __builtin_amdgcn_wave_barrier();

    // ---- consume seg 1 (receiver) ----
    MFMA_SEG(1)

    // write seg E (cvt fp32->fp16); prefetch GEMM2 B half-0 (K-steps 0..1)
    #pragma unroll
    for (int i = 0; i < 8; i++) {
        const int row = 2 * i + sub;
        *(f16x4*)(ab + row * 256 + ((c31 * 8) ^ ((row & 15) << 4))) = cvt4(ev[i]);
    }
    f16x8 b2fa[2][8];
    #pragma unroll
    for (int kk = 0; kk < 2; kk++)
        #pragma unroll
        for (int n = 0; n < 8; n++) {
            const int ks = kk * 4 + (lane >> 4);
            b2fa[kk][n] = *(const f16x8*)(w2f + ((size_t)(ks * 128 + n * 16 + r15)) * 8);
        }
    __builtin_amdgcn_wave_barrier();

    // ---- consume seg 2 (edge) ----
    MFMA_SEG(2)

    // ---- bias + relu, h -> same LDS buffer (seg data dead) ----
    #pragma unroll
    for (int n = 0; n < 8; n++) {
        const int col = n * 16 + r15;
        #pragma unroll
        for (int reg = 0; reg < 4; reg++) {
            const int row = (lane >> 4) * 4 + reg;
            float v = fmaxf(acc[n][reg] + b1v[n], 0.0f);
            *(_Float16*)(ab + row * 256 + ((col * 2) ^ ((row & 15) << 4))) = (_Float16)v;
        }
    }
    __builtin_amdgcn_wave_barrier();

    // ---------------- GEMM2: [16x128] @ [128x128] ----------------
    f32x4a acc2[8] = {};
    #pragma unroll
    for (int kk = 0; kk < 2; kk++) {
        f16x8 a = *(const f16x8*)(ab + r15 * 256 + ((kk * 64 + q16) ^ xa));
        #pragma unroll
        for (int n = 0; n < 8; n++)
            acc2[n] = __builtin_amdgcn_mfma_f32_16x16x32_f16(a, b2fa[kk][n], acc2[n], 0, 0, 0);
    }
    f16x8 b2fb[2][8];
    #pragma unroll
    for (int kk = 0; kk < 2; kk++)
        #pragma unroll
        for (int n = 0; n < 8; n++) {
            const int ks = (kk + 2) * 4 + (lane >> 4);
            b2fb[kk][n] = *(const f16x8*)(w2f + ((size_t)(ks * 128 + n * 16 + r15)) * 8);
        }
    #pragma unroll
    for (int kk = 2; kk < 4; kk++) {
        f16x8 a = *(const f16x8*)(ab + r15 * 256 + ((kk * 64 + q16) ^ xa));
        #pragma unroll
        for (int n = 0; n < 8; n++)
            acc2[n] = __builtin_amdgcn_mfma_f32_16x16x32_f16(a, b2fb[kk - 2][n], acc2[n], 0, 0, 0);
    }

    // ---- bias + store fp32 ----
    #pragma unroll
    for (int n = 0; n < 8; n++) {
        #pragma unroll
        for (int reg = 0; reg < 4; reg++) {
            const int row = (lane >> 4) * 4 + reg;
            __builtin_nontemporal_store(acc2[n][reg] + b2v[n],
                out + (size_t)(ebase + row) * DD + n * 16 + r15);
        }
    }
}

extern "C" void kernel_launch(void* const* d_in, const int* in_sizes, int n_in,
                              void* d_out, int out_size, void* d_ws, size_t ws_size,
                              hipStream_t stream) {
    const float* node_attr = (const float*)d_in[0];
    const int* eidx = (const int*)d_in[1];
    const float* edge_attr = (const float*)d_in[2];
    const float* w1 = (const float*)d_in[3];
    const float* b1 = (const float*)d_in[4];
    const float* w2 = (const float*)d_in[5];
    const float* b2 = (const float*)d_in[6];
    float* out = (float*)d_out;

    _Float16* w1t = (_Float16*)d_ws;            // 96KB swizzled
    _Float16* w2f = w1t + 384 * 128;            // 32KB fragment-major
    _Float16* nf16 = w2f + 128 * 128;           // 12.8MB fp16 node rows

    hipFuncSetAttribute((const void*)edge_mlp,
                        hipFuncAttributeMaxDynamicSharedMemorySize, 160 * 1024);

    prep_w<<<256, 256, 0, stream>>>(w1, w2, w1t, w2f);
    prep_node<<<3125, 256, 0, stream>>>(node_attr, nf16);
    edge_mlp<<<3125, 1024, 160 * 1024, stream>>>(node_attr, eidx, edge_attr,
                                                 w1t, b1, w2f, b2, nf16, out);
}

// Round 15
// 242.153 us; speedup vs baseline: 1.5603x; 1.5603x over previous
//
#include <hip/hip_runtime.h>

// EdgeBlock: out = relu(concat(node[snd], node[rcv], edge) @ w1 + b1) @ w2 + b2
// E=800000, N=50000, D=128. fp32 in/out, fp16 MFMA.
// r15 = r14 (16x16x32 tiles) with correct unified VGPR+AGPR budget math:
//   768-thr block (12 waves), LDS = 96KB w1t + 12*4KB = 144KB -> 1 blk/CU,
//   12 waves/CU = 3 waves/SIMD -> 170-reg budget >= ~120 live (no spill).
//   1.5x r11's occupancy. S->R->E order kept (r13: E-first is worse).

#define NE 800000
#define ND 50000
#define DD 128

typedef float f32x4v __attribute__((ext_vector_type(4)));
typedef float f32x4a __attribute__((ext_vector_type(4)));
typedef _Float16 f16x8 __attribute__((ext_vector_type(8)));
typedef _Float16 f16x4 __attribute__((ext_vector_type(4)));

__device__ __forceinline__ f16x4 cvt4(f32x4v v) {
    f16x4 r;
    r[0] = (_Float16)v[0]; r[1] = (_Float16)v[1];
    r[2] = (_Float16)v[2]; r[3] = (_Float16)v[3];
    return r;
}

// w1[384][128] -> w1t swizzled fp16: byte = col*768 + ((k*2) ^ ((col&15)<<4))   (96KB)
// w2[128][128] -> w2f fragment-major fp16: w2f[(ks*128 + col)*8 + j] = w2[ks*8+j][col] (32KB)
__global__ void prep_w(const float* __restrict__ w1, const float* __restrict__ w2,
                       _Float16* __restrict__ w1t, _Float16* __restrict__ w2f) {
    int i = blockIdx.x * 256 + threadIdx.x;   // 65536 total
    if (i < 384 * 128) {
        int col = i / 384;
        int k = i - col * 384;
        float v = w1[(size_t)k * 128 + col];
        int byteoff = col * 768 + ((k * 2) ^ ((col & 15) << 4));
        *(_Float16*)((char*)w1t + byteoff) = (_Float16)v;
    } else {
        int j = i - 384 * 128;                // 0..16383
        int ks = j >> 10;                     // 0..15
        int col = (j >> 3) & 127;
        int jj = j & 7;
        w2f[j] = (_Float16)w2[(size_t)(ks * 8 + jj) * 128 + col];
    }
}

// node_attr fp32 [50000][128] -> nf16 fp16 [50000][128]
__global__ void prep_node(const float* __restrict__ node_attr, _Float16* __restrict__ nf16) {
    int i = blockIdx.x * 256 + threadIdx.x;   // x8 elems: 3125 blocks
    const float* src = node_attr + (size_t)i * 8;
    f32x4v a = *(const f32x4v*)src;
    f32x4v b = *(const f32x4v*)(src + 4);
    f16x8 r;
    r[0] = (_Float16)a[0]; r[1] = (_Float16)a[1];
    r[2] = (_Float16)a[2]; r[3] = (_Float16)a[3];
    r[4] = (_Float16)b[0]; r[5] = (_Float16)b[1];
    r[6] = (_Float16)b[2]; r[7] = (_Float16)b[3];
    *(f16x8*)(nf16 + (size_t)i * 8) = r;
}

// MFMA over one staged segment: 4 K-steps (K=32 each) against w1t seg in LDS.
#define MFMA_SEG(SEG)                                                                     \
    _Pragma("unroll")                                                                     \
    for (int kk = 0; kk < 4; kk++) {                                                      \
        f16x8 a = *(const f16x8*)(ab + r15 * 256 + ((kk * 64 + q16) ^ xa));               \
        _Pragma("unroll")                                                                 \
        for (int n = 0; n < 8; n++) {                                                     \
            const int col = n * 16 + r15;                                                 \
            f16x8 b = *(const f16x8*)(lds + col * 768 +                                   \
                       ((((SEG) * 4 + kk) * 64 + q16) ^ xa));                             \
            acc[n] = __builtin_amdgcn_mfma_f32_16x16x32_f16(a, b, acc[n], 0, 0, 0);       \
        }                                                                                 \
    }

// write a gathered fp16 segment (V = f16x4[8], 2 rows/instr) into ab, swizzled
#define WRITE_SEG16(V)                                                                    \
    _Pragma("unroll")                                                                     \
    for (int i = 0; i < 8; i++) {                                                         \
        const int row = 2 * i + sub;                                                      \
        *(f16x4*)(ab + row * 256 + ((c31 * 8) ^ ((row & 15) << 4))) = V[i];               \
    }

__global__ __attribute__((amdgpu_flat_work_group_size(768, 768),
                          amdgpu_waves_per_eu(3, 3)))
void edge_mlp(
    const float* __restrict__ node_attr,   // unused
    const int* __restrict__ eidx,
    const float* __restrict__ edge_attr,
    const _Float16* __restrict__ w1t,   // swizzled, 96KB
    const float* __restrict__ b1,
    const _Float16* __restrict__ w2f,   // fragment-major, 32KB
    const float* __restrict__ b2,
    const _Float16* __restrict__ nf16,  // fp16 node rows, 12.8MB (L3-resident)
    float* __restrict__ out) {
    extern __shared__ char lds[];   // [0,96K): w1t swz   [96K + wid*4K): A/h per wave

    const int tid = threadIdx.x;
    const int wid = tid >> 6;        // 0..11
    const int lane = tid & 63;
    const int r15 = lane & 15;       // MFMA row / col low bits
    const int q16 = (lane >> 4) * 16;// k-slice byte offset (0..48)
    const int sub = lane >> 5;       // row selector within gathered pair
    const int c31 = lane & 31;       // chunk index within row

    // ---- stage w1t -> LDS ----
    {
        const char* src = (const char*)w1t;
        #pragma unroll
        for (int i = 0; i < 8; i++) {
            int off = (tid + i * 768) * 16;   // 768*8*16B = 96KB
            *(f16x8*)(lds + off) = *(const f16x8*)(src + off);
        }
    }

    float b1v[8], b2v[8];
    #pragma unroll
    for (int n = 0; n < 8; n++) { b1v[n] = b1[n * 16 + r15]; b2v[n] = b2[n * 16 + r15]; }

    __syncthreads();

    char* ab = lds + 96 * 1024 + wid * 4096;
    const int xa = r15 << 4;          // swizzle XOR
    int ebase = blockIdx.x * 192 + wid * 16;
    if (ebase > NE - 16) ebase = NE - 16;   // tail clamp (idempotent dup writes)

    const int sidx = eidx[ebase + r15];
    const int ridx = eidx[NE + ebase + r15];

    // ---- gather sender rows: fp16, 2 rows/instr (2x256B), 8B/lane ----
    f16x4 sv[8];
    #pragma unroll
    for (int i = 0; i < 8; i++) {
        int r = __shfl(sidx, 2 * i + sub);
        sv[i] = *(const f16x4*)(nf16 + (size_t)r * DD + c31 * 4);
    }
    WRITE_SEG16(sv)

    // issue receiver gathers (fly during seg-S MFMAs)
    f16x4 rv[8];
    #pragma unroll
    for (int i = 0; i < 8; i++) {
        int r = __shfl(ridx, 2 * i + sub);
        rv[i] = *(const f16x4*)(nf16 + (size_t)r * DD + c31 * 4);
    }

    f32x4a acc[8] = {};
    __builtin_amdgcn_wave_barrier();

    // ---- consume seg 0 (sender) ----
    MFMA_SEG(0)

    WRITE_SEG16(rv)
    // issue edge loads (fp32, 2 rows/instr = 2x512B, 16B/lane)
    f32x4v ev[8];
    #pragma unroll
    for (int i = 0; i < 8; i++) {
        const int row = 2 * i + sub;
        ev[i] = __builtin_nontemporal_load(
            (const f32x4v*)(edge_attr + (size_t)(ebase + row) * DD + c31 * 4));
    }
    __builtin_amdgcn_wave_barrier();

    // ---- consume seg 1 (receiver) ----
    MFMA_SEG(1)

    // write seg E (cvt fp32->fp16); prefetch GEMM2 B half-0
    #pragma unroll
    for (int i = 0; i < 8; i++) {
        const int row = 2 * i + sub;
        *(f16x4*)(ab + row * 256 + ((c31 * 8) ^ ((row & 15) << 4))) = cvt4(ev[i]);
    }
    f16x8 b2fa[2][8];
    #pragma unroll
    for (int kk = 0; kk < 2; kk++)
        #pragma unroll
        for (int n = 0; n < 8; n++) {
            const int ks = kk * 4 + (lane >> 4);
            b2fa[kk][n] = *(const f16x8*)(w2f + ((size_t)(ks * 128 + n * 16 + r15)) * 8);
        }
    __builtin_amdgcn_wave_barrier();

    // ---- consume seg 2 (edge) ----
    MFMA_SEG(2)

    // ---- bias + relu, h -> same LDS buffer (seg data dead) ----
    #pragma unroll
    for (int n = 0; n < 8; n++) {
        const int col = n * 16 + r15;
        #pragma unroll
        for (int reg = 0; reg < 4; reg++) {
            const int row = (lane >> 4) * 4 + reg;
            float v = fmaxf(acc[n][reg] + b1v[n], 0.0f);
            *(_Float16*)(ab + row * 256 + ((col * 2) ^ ((row & 15) << 4))) = (_Float16)v;
        }
    }
    __builtin_amdgcn_wave_barrier();

    // ---------------- GEMM2: [16x128] @ [128x128] ----------------
    f32x4a acc2[8] = {};
    #pragma unroll
    for (int kk = 0; kk < 2; kk++) {
        f16x8 a = *(const f16x8*)(ab + r15 * 256 + ((kk * 64 + q16) ^ xa));
        #pragma unroll
        for (int n = 0; n < 8; n++)
            acc2[n] = __builtin_amdgcn_mfma_f32_16x16x32_f16(a, b2fa[kk][n], acc2[n], 0, 0, 0);
    }
    f16x8 b2fb[2][8];
    #pragma unroll
    for (int kk = 0; kk < 2; kk++)
        #pragma unroll
        for (int n = 0; n < 8; n++) {
            const int ks = (kk + 2) * 4 + (lane >> 4);
            b2fb[kk][n] = *(const f16x8*)(w2f + ((size_t)(ks * 128 + n * 16 + r15)) * 8);
        }
    #pragma unroll
    for (int kk = 2; kk < 4; kk++) {
        f16x8 a = *(const f16x8*)(ab + r15 * 256 + ((kk * 64 + q16) ^ xa));
        #pragma unroll
        for (int n = 0; n < 8; n++)
            acc2[n] = __builtin_amdgcn_mfma_f32_16x16x32_f16(a, b2fb[kk - 2][n], acc2[n], 0, 0, 0);
    }

    // ---- bias + store fp32 ----
    #pragma unroll
    for (int n = 0; n < 8; n++) {
        #pragma unroll
        for (int reg = 0; reg < 4; reg++) {
            const int row = (lane >> 4) * 4 + reg;
            __builtin_nontemporal_store(acc2[n][reg] + b2v[n],
                out + (size_t)(ebase + row) * DD + n * 16 + r15);
        }
    }
}

extern "C" void kernel_launch(void* const* d_in, const int* in_sizes, int n_in,
                              void* d_out, int out_size, void* d_ws, size_t ws_size,
                              hipStream_t stream) {
    const float* node_attr = (const float*)d_in[0];
    const int* eidx = (const int*)d_in[1];
    const float* edge_attr = (const float*)d_in[2];
    const float* w1 = (const float*)d_in[3];
    const float* b1 = (const float*)d_in[4];
    const float* w2 = (const float*)d_in[5];
    const float* b2 = (const float*)d_in[6];
    float* out = (float*)d_out;

    _Float16* w1t = (_Float16*)d_ws;            // 96KB swizzled
    _Float16* w2f = w1t + 384 * 128;            // 32KB fragment-major
    _Float16* nf16 = w2f + 128 * 128;           // 12.8MB fp16 node rows

    hipFuncSetAttribute((const void*)edge_mlp,
                        hipFuncAttributeMaxDynamicSharedMemorySize, 160 * 1024);

    prep_w<<<256, 256, 0, stream>>>(w1, w2, w1t, w2f);
    prep_node<<<3125, 256, 0, stream>>>(node_attr, nf16);
    // 4167 blocks x 192 edges = 800,064 (tail clamped)
    edge_mlp<<<4167, 768, 144 * 1024, stream>>>(node_attr, eidx, edge_attr,
                                                w1t, b1, w2f, b2, nf16, out);
}